// Round 14
// baseline (790.951 us; speedup 1.0000x reference)
//
#include <hip/hip_runtime.h>
#include <math.h>

#define DIMK 2048
#define NEMB 16384
#define NB 256
#define NR2 1536          // 256*6 neighbor rows
#define INV_BETA 20.0f
#define NEG_INF (-3.0e38f)
#define PBV_BLOCKS 124

typedef short short8 __attribute__((ext_vector_type(8)));
typedef float f32x4 __attribute__((ext_vector_type(4)));

__device__ __forceinline__ unsigned short f2bf(float f) {
  unsigned u = __float_as_uint(f);
  u += 0x7fffu + ((u >> 16) & 1u);
  return (unsigned short)(u >> 16);
}
__device__ __forceinline__ float bf2f(unsigned short u) {
  return __uint_as_float(((unsigned)u) << 16);
}

// top-6 insert with (value desc, index asc) tie-break — matches jax top_k order
__device__ __forceinline__ void ins6i(float x, int xi, float v[6], int vi[6]) {
  if (x > v[5] || (x == v[5] && xi < vi[5])) {
    v[5] = x; vi[5] = xi;
#pragma unroll
    for (int j = 5; j > 0; j--) {
      if (v[j] > v[j - 1] || (v[j] == v[j - 1] && vi[j] < vi[j - 1])) {
        float tv = v[j]; v[j] = v[j - 1]; v[j - 1] = tv;
        int ti = vi[j]; vi[j] = vi[j - 1]; vi[j - 1] = ti;
      }
    }
  }
}

// fused bf16 conversion of em (blocks 0..32767) and x (blocks 32768..33279)
__global__ __launch_bounds__(256) void cvt2_kernel(const float* __restrict__ em,
                                                   const float* __restrict__ x,
                                                   unsigned short* __restrict__ em_bf,
                                                   unsigned short* __restrict__ x_bf) {
  int b = blockIdx.x, t = threadIdx.x;
  const float* src;
  unsigned short* dst;
  int i;
  if (b < 32768) { src = em; dst = em_bf; i = b * 256 + t; }
  else           { src = x;  dst = x_bf;  i = (b - 32768) * 256 + t; }
  float4 f = ((const float4*)src)[i];
  ushort4 o;
  o.x = f2bf(f.x); o.y = f2bf(f.y); o.z = f2bf(f.z); o.w = f2bf(f.w);
  ((ushort4*)dst)[i] = o;
}

// ---------------- reg-staged GEMM template (R9's verified 2-deep loop) ----------------
// MODE 0: logits = X(256xK)@em^T * 20. NKC=64, grid (128,4,1). [R9-exact]
// MODE 1: sims phase A partials — 1280 NON-ANCHOR rows (slot s -> row (s/5)*6+s%5+1;
//         anchor rows: count==0 -> recip=1 always). cols 0..512, K-split z=16, NKC=4,
//         grid (4,10,16)=640 blocks (one batch). out simsA[kz][1280][512].
template <int MODE>
__global__ __launch_bounds__(256, 3) void gemm_rs(
    const unsigned short* __restrict__ Abase, const unsigned short* __restrict__ Bbase,
    const int* __restrict__ nidx, float* __restrict__ outP) {
  constexpr int MTILE = (MODE == 0) ? 64 : 128;
  constexpr int MI = 4;
  constexpr int NI = (MODE == 0) ? 2 : 4;
  constexpr int NSUB_A = MTILE / 16;   // 4 or 8
  constexpr int NSUB = NSUB_A + 8;     // 12 or 16
  constexpr int NA = NSUB / 4;
  constexpr int NKC = (MODE == 1) ? 4 : 64;
  constexpr int OSTRIDE = (MODE == 0) ? 16384 : 512;
  constexpr size_t PLANE = (size_t)1280 * 512;

  __shared__ unsigned short st[2][NSUB * 512];
  __shared__ int rowIdxSh[128];
  int t = threadIdx.x;
  int lane = t & 63, wave = t >> 6;
  int quad = lane >> 4, l16 = lane & 15;
  int wr = (MODE == 0) ? 0 : (wave >> 1);
  int wc = (MODE == 0) ? wave : (wave & 1);
  int bn = blockIdx.x, bm = blockIdx.y, kz = blockIdx.z;

  if constexpr (MODE == 1) {
    if (t < 128) {
      int slot = bm * 128 + t;
      int g = (slot / 5) * 6 + (slot % 5) + 1;   // skip k=0 (anchor-self) rows
      rowIdxSh[t] = nidx[g];
    }
    __syncthreads();
  }

  int kbase = (MODE == 1) ? kz * (NKC * 32) : 0;

  const unsigned short* agp[NA];
  int soff[NA];
  {
    int seg = lane >> 4;
#pragma unroll
    for (int a = 0; a < NA; a++) {
      int s = wave + a * 4;
      size_t grow;
      const unsigned short* basep;
      if (s < NSUB_A) {
        int r = s * 16 + l16;
        grow = (MODE == 0) ? (size_t)(bm * MTILE + r) : (size_t)rowIdxSh[r];
        basep = Abase;
      } else {
        grow = (size_t)(bn * 128 + (s - NSUB_A) * 16 + l16);
        basep = Bbase;
      }
      agp[a] = basep + grow * DIMK + kbase + seg * 8;
      soff[a] = s * 512;
    }
  }

  f32x4 acc[MI][NI];
#pragma unroll
  for (int mi = 0; mi < MI; mi++)
#pragma unroll
    for (int ni = 0; ni < NI; ni++) acc[mi][ni] = (f32x4)0.0f;

  int lo = lane * 8;

  short8 rA[NA], rB2[NA];
  auto LOADT = [&](short8* R, int kk) {
#pragma unroll
    for (int a = 0; a < NA; a++) R[a] = *(const short8*)(agp[a] + kk * 32);
  };
  auto WRITET = [&](const short8* R, int b) {
#pragma unroll
    for (int a = 0; a < NA; a++) *(short8*)&st[b][soff[a] + lo] = R[a];
  };
  auto COMPUTE = [&](int b) {
    const unsigned short* hb = &st[b][0];
    short8 af[MI], bfv[NI];
#pragma unroll
    for (int mi = 0; mi < MI; mi++)
      af[mi] = *(const short8*)&hb[(wr * MI + mi) * 512 + lo];
#pragma unroll
    for (int ni = 0; ni < NI; ni++)
      bfv[ni] = *(const short8*)&hb[(NSUB_A + wc * NI + ni) * 512 + lo];
#pragma unroll
    for (int mi = 0; mi < MI; mi++)
#pragma unroll
      for (int ni = 0; ni < NI; ni++)
        acc[mi][ni] =
            __builtin_amdgcn_mfma_f32_16x16x32_bf16(af[mi], bfv[ni], acc[mi][ni], 0, 0, 0);
  };

  LOADT(rA, 0);
  LOADT(rB2, 1);
  WRITET(rA, 0);
  __syncthreads();
  for (int k = 0; k < NKC; k += 2) {
    if (k + 2 < NKC) LOADT(rA, k + 2);
    COMPUTE(0);
    WRITET(rB2, 1);
    __syncthreads();
    if (k + 3 < NKC) LOADT(rB2, k + 3);
    COMPUTE(1);
    if (k + 2 < NKC) WRITET(rA, 0);
    __syncthreads();
  }

  if constexpr (MODE == 0) {
#pragma unroll
    for (int mi = 0; mi < MI; mi++) {
      int row = bm * MTILE + mi * 16 + quad * 4;
#pragma unroll
      for (int ni = 0; ni < NI; ni++) {
        int col = bn * 128 + wave * 32 + ni * 16 + l16;
#pragma unroll
        for (int rr = 0; rr < 4; rr++)
          outP[(size_t)(row + rr) * OSTRIDE + col] = acc[mi][ni][rr] * INV_BETA;
      }
    }
  } else {
    float* op = outP + (size_t)kz * PLANE;
#pragma unroll
    for (int mi = 0; mi < MI; mi++) {
#pragma unroll
      for (int ni = 0; ni < NI; ni++) {
        int col = bn * 128 + wc * 64 + ni * 16 + l16;
#pragma unroll
        for (int rr = 0; rr < 4; rr++) {
          int row = bm * 128 + wr * 64 + mi * 16 + quad * 4 + rr;
          op[(size_t)row * OSTRIDE + col] = acc[mi][ni][rr];
        }
      }
    }
  }
}

// count phase A: cnt[g] += #(sum of 16 K-partials > sa[g]) over cols 0..512
__global__ __launch_bounds__(256) void countA_kernel(const float* __restrict__ simsA,
                                                     const float* __restrict__ sa,
                                                     int* __restrict__ cnt) {
  int t = threadIdx.x, lane = t & 63;
  constexpr size_t PL = (size_t)1280 * 512;
  for (int it = blockIdx.x; it < 1280 * 2; it += 256) {
    int slot = it >> 1, cx = it & 1;
    int g = (slot / 5) * 6 + (slot % 5) + 1;
    size_t o = (size_t)slot * 512 + cx * 256 + t;
    float s = 0.f;
#pragma unroll
    for (int p = 0; p < 16; p++) s += simsA[o + (size_t)p * PL];
    int c = (s > sa[g]) ? 1 : 0;
#pragma unroll
    for (int off = 32; off > 0; off >>= 1) c += __shfl_down(c, off, 64);
    if (lane == 0 && c > 0) atomicAdd(&cnt[g], c);
  }
}

// rowstats + fused sa: per-row top6 / lse, then waves 0-5 compute the 6 exact fp32
// anchor dots (identical loop to old sa_kernel), zero cnt and the pbv ticket.
__global__ __launch_bounds__(1024) void rowstats_sa_kernel(
    const float* __restrict__ logits, const float* __restrict__ em,
    float* __restrict__ topv, int* __restrict__ topi, float* __restrict__ lse,
    float* __restrict__ sa, int* __restrict__ cnt, int* __restrict__ done) {
  int m = blockIdx.x, t = threadIdx.x;
  int lane = t & 63, wave = t >> 6;
  const float4* row4 = (const float4*)(logits + (size_t)m * NEMB);
  float v6[6]; int i6[6];
#pragma unroll
  for (int j = 0; j < 6; j++) { v6[j] = NEG_INF; i6[j] = 0x7fffffff; }
  float vals[16];
#pragma unroll
  for (int j = 0; j < 4; j++) {
    float4 f = row4[t + j * 1024];
    vals[j * 4 + 0] = f.x; vals[j * 4 + 1] = f.y;
    vals[j * 4 + 2] = f.z; vals[j * 4 + 3] = f.w;
  }
  float mx = vals[0];
#pragma unroll
  for (int r = 1; r < 16; r++) mx = fmaxf(mx, vals[r]);
  float sme = 0.f;
#pragma unroll
  for (int r = 0; r < 16; r++) sme += expf(vals[r] - mx);
#pragma unroll
  for (int j = 0; j < 4; j++) {
    int base = (t + j * 1024) * 4;
#pragma unroll
    for (int b = 0; b < 4; b++) ins6i(vals[j * 4 + b], base + b, v6, i6);
  }
  __shared__ float sv[1024 * 6]; __shared__ int si[1024 * 6];
  __shared__ float smx[1024], ssm[1024];
#pragma unroll
  for (int j = 0; j < 6; j++) { sv[t * 6 + j] = v6[j]; si[t * 6 + j] = i6[j]; }
  smx[t] = mx; ssm[t] = sme;
  __syncthreads();
  for (int s = 512; s > 0; s >>= 1) {
    if (t < s) {
      float mo = smx[t + s], lo2 = ssm[t + s];
      float mn = fmaxf(smx[t], mo);
      ssm[t] = ssm[t] * expf(smx[t] - mn) + lo2 * expf(mo - mn);
      smx[t] = mn;
#pragma unroll
      for (int j = 0; j < 6; j++) ins6i(sv[(t + s) * 6 + j], si[(t + s) * 6 + j], v6, i6);
#pragma unroll
      for (int j = 0; j < 6; j++) { sv[t * 6 + j] = v6[j]; si[t * 6 + j] = i6[j]; }
    }
    __syncthreads();
  }
  if (t == 0) {
    lse[m] = smx[0] + logf(ssm[0]);
#pragma unroll
    for (int j = 0; j < 6; j++) { topv[m * 6 + j] = v6[j]; topi[m * 6 + j] = i6[j]; }
    if (m == 0) done[0] = 0;
  }
  // fused sa: si[0..5] holds the final top-6 indices after the merge
  if (wave < 6) {
    int ii = si[wave], aa = si[0];
    const float* ei = em + (size_t)ii * DIMK;
    const float* ea = em + (size_t)aa * DIMK;
    float s = 0.f;
    for (int d = lane; d < DIMK; d += 64) s += ei[d] * ea[d];
#pragma unroll
    for (int off = 32; off > 0; off >>= 1) s += __shfl_down(s, off, 64);
    if (lane == 0) { sa[m * 6 + wave] = s; cnt[m * 6 + wave] = 0; }
  }
}

// phase B VALU kernel: each block owns 128 cols of [512,16384); scans cnt itself to
// find survivors (no compact kernel, any ns); caches <=16 survivor rows (bf16) in LDS;
// per-col lane-strided dots + shuffle reduce; LDS counts -> one atomicAdd per row.
// Last block (ticket) runs the final reduction.
__global__ __launch_bounds__(256) void pbv_kernel(
    const unsigned short* __restrict__ em_bf, const int* __restrict__ topi,
    const float* __restrict__ sa, int* __restrict__ cnt, int* __restrict__ done,
    const float* __restrict__ logits, const float* __restrict__ topv,
    const float* __restrict__ lse_arr, const int* __restrict__ targets,
    float* __restrict__ out) {
  __shared__ int survSh[1536];
  __shared__ int nsSh;
  __shared__ unsigned short rowsSh[16][2048];   // 64 KB
  __shared__ int ldsCnt[16];
  __shared__ int lastFlag;
  __shared__ float sA[256], sB2[256];
  int t = threadIdx.x, lane = t & 63, wave = t >> 6;
  if (t == 0) nsSh = 0;
  __syncthreads();
  for (int i = t; i < NR2; i += 256) {
    if ((i % 6) != 0 && cnt[i] < 6) {
      int p = atomicAdd(&nsSh, 1);
      survSh[p] = i;
    }
  }
  __syncthreads();
  int ns = nsSh;
  int colbase = 512 + blockIdx.x * 128;

  for (int g = 0; g < ns; g += 16) {
    int gsz = (ns - g < 16) ? (ns - g) : 16;
    for (int ri = 0; ri < gsz; ri++) {
      int r = topi[survSh[g + ri]];
      ((short8*)&rowsSh[ri][0])[t] = ((const short8*)(em_bf + (size_t)r * DIMK))[t];
    }
    if (t < 16) ldsCnt[t] = 0;
    __syncthreads();
    for (int j = 0; j < 32; j++) {
      int col = colbase + wave * 32 + j;
      const short8* cp = (const short8*)(em_bf + (size_t)col * DIMK + lane * 32);
      short8 c0 = cp[0], c1 = cp[1], c2 = cp[2], c3 = cp[3];
      float cf[32];
#pragma unroll
      for (int e = 0; e < 8; e++) {
        cf[e] = bf2f((unsigned short)c0[e]);
        cf[8 + e] = bf2f((unsigned short)c1[e]);
        cf[16 + e] = bf2f((unsigned short)c2[e]);
        cf[24 + e] = bf2f((unsigned short)c3[e]);
      }
      for (int ri = 0; ri < gsz; ri++) {
        const unsigned short* rp = &rowsSh[ri][lane * 32];
        float s = 0.f;
#pragma unroll
        for (int e = 0; e < 32; e++) s += cf[e] * bf2f(rp[e]);
#pragma unroll
        for (int off = 32; off > 0; off >>= 1) s += __shfl_down(s, off, 64);
        if (lane == 0 && s > sa[survSh[g + ri]]) atomicAdd(&ldsCnt[ri], 1);
      }
    }
    __syncthreads();
    if (t < gsz) {
      if (ldsCnt[t] > 0) atomicAdd(&cnt[survSh[g + t]], ldsCnt[t]);
    }
    __syncthreads();
  }

  // last-block ticket -> final reduction
  __threadfence();
  if (t == 0) {
    int old = atomicAdd(done, 1);
    lastFlag = (old == PBV_BLOCKS - 1) ? 1 : 0;
  }
  __syncthreads();
  if (!lastFlag) return;
  __threadfence();
  {
    int m = t;
    float lse = lse_arr[m];
    int tgt = targets[m];
    float tl = logits[(size_t)m * NEMB + tgt];
    float beta = 0.f, Ps = 0.f, nbp = 0.f;
    bool tin = false;
#pragma unroll
    for (int k = 0; k < 6; k++) {
      int idx = topi[m * 6 + k]; float v = topv[m * 6 + k];
      float p = expf(v - lse);
      if (idx == tgt) { tin = true; beta += (lse - v); Ps += p; }
      else if (cnt[m * 6 + k] < 6) { beta += 0.5f * (lse - v); Ps += p; nbp += p; }
    }
    if (!tin) { beta += (lse - tl); Ps += expf(tl - lse); }
    float alpha = 9.2103404f * (1.f - Ps) + 0.6931472f * nbp;
    sA[m] = alpha; sB2[m] = beta;
    __syncthreads();
    for (int s = 128; s > 0; s >>= 1) {
      if (m < s) { sA[m] += sA[m + s]; sB2[m] += sB2[m + s]; }
      __syncthreads();
    }
    if (m == 0) { out[0] = 0.05f * sA[0] / 256.f; out[1] = sB2[0] / 256.f; }
  }
}

extern "C" void kernel_launch(void* const* d_in, const int* in_sizes, int n_in,
                              void* d_out, int out_size, void* d_ws, size_t ws_size,
                              hipStream_t stream) {
  const float* x = (const float*)d_in[0];
  const float* em = (const float*)d_in[1];
  const int* targets = (const int*)d_in[2];
  char* ws = (char*)d_ws;
  unsigned short* em_bf = (unsigned short*)ws;                 // 64 MB
  unsigned short* x_bf  = (unsigned short*)(ws + 67108864);    // 1 MB
  float* logits = (float*)(ws + 68157440);                     // 16 MB
  float* simsA  = (float*)(ws + 84934656);                     // 16 x 2.5 MB = 40 MB
  int*   cnt    = (int*)  (ws + 126877696);                    // 6144 B
  float* topv   = (float*)(ws + 126883840);                    // 6144 B
  int*   topi   = (int*)  (ws + 126889984);                    // 6144 B
  float* lse    = (float*)(ws + 126896128);                    // 1024 B
  float* sa     = (float*)(ws + 126897152);                    // 6144 B
  int*   done   = (int*)  (ws + 126903296);                    // 64 B

  cvt2_kernel<<<dim3(33280), dim3(256), 0, stream>>>(em, x, em_bf, x_bf);
  gemm_rs<0><<<dim3(128, 4, 1), dim3(256), 0, stream>>>(x_bf, em_bf, (const int*)nullptr,
                                                        logits);
  rowstats_sa_kernel<<<dim3(256), dim3(1024), 0, stream>>>(logits, em, topv, topi, lse,
                                                           sa, cnt, done);
  gemm_rs<1><<<dim3(4, 10, 16), dim3(256), 0, stream>>>(em_bf, em_bf, topi, simsA);
  countA_kernel<<<dim3(256), dim3(256), 0, stream>>>(simsA, sa, cnt);
  pbv_kernel<<<dim3(PBV_BLOCKS), dim3(256), 0, stream>>>(em_bf, topi, sa, cnt, done,
                                                         logits, topv, lse, targets,
                                                         (float*)d_out);
}